// Round 9
// baseline (149.767 us; speedup 1.0000x reference)
//
#include <hip/hip_runtime.h>
#include <math.h>

__device__ __forceinline__ float4 f4max(float4 a, float4 b) {
    return make_float4(fmaxf(a.x, b.x), fmaxf(a.y, b.y), fmaxf(a.z, b.z), fmaxf(a.w, b.w));
}
__device__ __forceinline__ float4 f4scale(float s, float4 v) {
    return make_float4(s * v.x, s * v.y, s * v.z, s * v.w);
}
__device__ __forceinline__ float4 f4add(float4 a, float4 b) {
    return make_float4(a.x + b.x, a.y + b.y, a.z + b.z, a.w + b.w);
}
__device__ __forceinline__ float4 f4fma(float a, float4 b, float4 c) {  // scalar*vec+vec
    return make_float4(fmaf(a, b.x, c.x), fmaf(a, b.y, c.y), fmaf(a, b.z, c.z), fmaf(a, b.w, c.w));
}
__device__ __forceinline__ float4 f4fma4(float4 a, float4 b, float4 c) { // elementwise
    return make_float4(fmaf(a.x, b.x, c.x), fmaf(a.y, b.y, c.y),
                       fmaf(a.z, b.z, c.z), fmaf(a.w, b.w, c.w));
}

// agent-scope (sc1) relaxed stores: data goes to LLC, visible cross-XCD after
// vmcnt(0) drain — no wbl2 flush needed (R4/R5-verified, absmax 0.0).
__device__ __forceinline__ void store_f4_llc(float* p, float4 v) {
    __hip_atomic_store(p + 0, v.x, __ATOMIC_RELAXED, __HIP_MEMORY_SCOPE_AGENT);
    __hip_atomic_store(p + 1, v.y, __ATOMIC_RELAXED, __HIP_MEMORY_SCOPE_AGENT);
    __hip_atomic_store(p + 2, v.z, __ATOMIC_RELAXED, __HIP_MEMORY_SCOPE_AGENT);
    __hip_atomic_store(p + 3, v.w, __ATOMIC_RELAXED, __HIP_MEMORY_SCOPE_AGENT);
}

// R9: agent-scope relaxed LOADS — the dual of store_f4_llc. Lowered with
// sc0+sc1 set: bypass L1 and the XCD L2, read the LLC directly. This replaces
// the sync's buffer_inv acquire fence (which nuked ALL cached state — x's
// 4MB L2 copy included — every sync; the refill latency was booked inside
// the phases and was the ~15us/sync quantum, per R7/R8 falsifications).
// The generation poll (same instruction class) has observed cross-XCD LLC
// updates without any fence since R4 — direct evidence this path is coherent.
__device__ __forceinline__ float load_f_llc(const float* p) {
    return __hip_atomic_load(p, __ATOMIC_RELAXED, __HIP_MEMORY_SCOPE_AGENT);
}
__device__ __forceinline__ float4 load_f4_llc(const float* p) {
    return make_float4(load_f_llc(p + 0), load_f_llc(p + 1),
                       load_f_llc(p + 2), load_f_llc(p + 3));
}

// Wave-level sparsemax (verified R2-R8): lane holds element `lane` of a 64-vector.
__device__ __forceinline__ float wave_sparsemax(float z, int lane) {
    float v = z;
    for (int k = 2; k <= 64; k <<= 1) {
        bool desc = (lane & k) == 0;
        for (int j = k >> 1; j > 0; j >>= 1) {
            float other = __shfl_xor(v, j, 64);
            bool lower = (lane & j) == 0;
            float mn = fminf(v, other), mx = fmaxf(v, other);
            v = (desc ^ lower) ? mn : mx;
        }
    }
    float c = v;
    for (int d = 1; d < 64; d <<= 1) {
        float n = __shfl_up(c, d, 64);
        if (lane >= d) c += n;
    }
    bool sup = (1.0f + (float)(lane + 1) * v) > c;
    int ksel = __popcll(__ballot(sup));
    float zk = __shfl(c, ksel - 1, 64);
    float tau = (zk - 1.0f) / (float)ksel;
    return fmaxf(z - tau, 0.f);
}

// ---------------------------------------------------------------------------
// Relaxed-only sync point, R9: NO acquire fence at all. Cross-sync data (P,
// h0) is read via load_f_llc/load_f4_llc (LLC-direct), so no cache
// maintenance is needed and x/W stay warm in L1/L2 across phases. Writer
// side: sc1 stores drained by __syncthreads()'s vmcnt(0) before arrival.
// Arrival: relaxed tree fetch_adds (16 lines of 16, then 16 leaders on one
// line; monotonic counters, a%16==15 elects — no resets, graph-replay-safe).
// Last leader bumps generation (relaxed); waiters spin on relaxed LLC loads.
// In-order waves + control dependency order the post-spin LLC loads.
// ---------------------------------------------------------------------------
__device__ unsigned g_grp[16 * 64];   // one counter per 256B line
__device__ unsigned g_glb;
__device__ unsigned g_gen1;
__device__ unsigned g_gen2;

__device__ __forceinline__ void sync_point(int bx, unsigned snap, unsigned* genp,
                                           bool wait) {
    __syncthreads();   // vmcnt(0): this block's sc1 stores are acked at LLC
    if (threadIdx.x == 0) {
        unsigned a = __hip_atomic_fetch_add(&g_grp[(bx & 15) << 6], 1u,
                                            __ATOMIC_RELAXED, __HIP_MEMORY_SCOPE_AGENT);
        if ((a & 15u) == 15u) {
            unsigned ga = __hip_atomic_fetch_add(&g_glb, 1u, __ATOMIC_RELAXED,
                                                 __HIP_MEMORY_SCOPE_AGENT);
            if ((ga & 15u) == 15u)
                __hip_atomic_fetch_add(genp, 1u, __ATOMIC_RELAXED,
                                       __HIP_MEMORY_SCOPE_AGENT);
        }
        if (wait) {
            while (__hip_atomic_load(genp, __ATOMIC_RELAXED,
                                     __HIP_MEMORY_SCOPE_AGENT) == snap)
                __builtin_amdgcn_s_sleep(1);
        }
    }
    if (wait) __syncthreads();
}

// ---------------------------------------------------------------------------
// Fused pipeline, ONE plain kernel, 256 blocks x 256 threads (R5 structure —
// R8's 512-thread variant was neutral, reverted).
// Mapping: 256 blocks = 16 t-chunks(16 t) x 16 B-chunks(4 B).
// Phase A : gram partials -> P via sc1 stores.          [sync1, no fence]
// Phase B'': wave w reduces gram row Bc+w via LLC loads (bitwise-identical
//            summation order) + sparsemax -> LDS psm_s[4][64].
// Phase C : agg0+W0+relu -> h0 via sc1 stores; x read NORMALLY (L1/L2 warm
//           from Phase A — no inv happened).            [sync2, no fence]
// Phase D : tail (blocks 0..63); h0 read via LLC loads.
// ---------------------------------------------------------------------------
__global__ __launch_bounds__(256)
void fused_gcn(const float* __restrict__ x, const float* __restrict__ W0,
               const float* __restrict__ W1, const float* __restrict__ Wp,
               float* __restrict__ P, float* __restrict__ h0,
               float* __restrict__ out) {
    __shared__ float xsT[64][68];                 // Phase A
    __shared__ float pstg[4][4][64];              // Phase B'' quarter sums
    __shared__ float psm_s[4][64];                // Phase B'' sparsemax out
    __shared__ __align__(16) float row[4 * 260];  // Phase D
    __shared__ float part[256];                   // Phase D
    __shared__ float psmD[64];                    // Phase D
    __shared__ float red[16];                     // Phase D

    int tid = threadIdx.x;
    int bx = blockIdx.x;
    int lane = tid & 63;

    unsigned snap1 = 0, snap2 = 0;
    if (tid == 0) {
        snap1 = __hip_atomic_load(&g_gen1, __ATOMIC_RELAXED, __HIP_MEMORY_SCOPE_AGENT);
        snap2 = __hip_atomic_load(&g_gen2, __ATOMIC_RELAXED, __HIP_MEMORY_SCOPE_AGENT);
    }

    // ---------------- Phase A: gram partials (R3-verified structure) -------
    {
        int k0 = bx * 64;
#pragma unroll
        for (int it = 0; it < 4; ++it) {
            int f = it * 256 + tid;
            int i = f >> 4, k4 = (f & 15) * 4;
            float4 v = *(const float4*)(x + (size_t)i * 16384 + k0 + k4);
            xsT[k4 + 0][i] = v.x; xsT[k4 + 1][i] = v.y;
            xsT[k4 + 2][i] = v.z; xsT[k4 + 3][i] = v.w;
        }
        __syncthreads();
        int ti = (tid >> 4) * 4, tj = (tid & 15) * 4;
        float4 a0 = make_float4(0, 0, 0, 0), a1 = a0, a2 = a0, a3 = a0;
#pragma unroll 8
        for (int k = 0; k < 64; ++k) {
            float4 a = *(const float4*)&xsT[k][ti];
            float4 b = *(const float4*)&xsT[k][tj];
            a0 = f4fma(a.x, b, a0); a1 = f4fma(a.y, b, a1);
            a2 = f4fma(a.z, b, a2); a3 = f4fma(a.w, b, a3);
        }
        float* basep = P + ((size_t)bx << 12);
        store_f4_llc(basep + (ti + 0) * 64 + tj, a0);
        store_f4_llc(basep + (ti + 1) * 64 + tj, a1);
        store_f4_llc(basep + (ti + 2) * 64 + tj, a2);
        store_f4_llc(basep + (ti + 3) * 64 + tj, a3);
    }
    sync_point(bx, snap1, &g_gen1, true);

    // ---------------- Phase B'': per-wave 1-row reduce + sparsemax ---------
    // Wave w reduces gram row Bc+w via LLC-direct loads. Lane (sub=lane>>4,
    // c16=lane&15) sums quarter sub (64 sequential chunks, LEFT-ASSOC —
    // bitwise identical to the verified reduce_sm). Cross-quarter combine
    // scalar left-assoc via LDS.
    {
        int w4 = tid >> 6;
        int Bc = (bx & 15) * 4;
        int rowi = Bc + w4;
        int sub = (tid & 63) >> 4;
        int c16 = tid & 15;
        const float* pb = P + (size_t)rowi * 64 + c16 * 4;
        int cbase = sub * 64;
        float4 g = make_float4(0, 0, 0, 0);
#pragma unroll 8
        for (int c = 0; c < 64; ++c)
            g = f4add(g, load_f4_llc(pb + ((size_t)(cbase + c) << 12)));
        *(float4*)&pstg[w4][sub][c16 * 4] = g;
        __syncthreads();
        {
            float z = (((pstg[w4][0][lane] + pstg[w4][1][lane])
                        + pstg[w4][2][lane]) + pstg[w4][3][lane]) * (1.0f / 256.0f);
            psm_s[w4][lane] = wave_sparsemax(z, lane);
        }
        __syncthreads();
    }

    // ---------------- Phase C: agg0 + W0 + relu -> h0 ----------------------
    // Block: t0 = (bx>>4)*16 (16 t's), Bc = (bx&15)*4 (4 B's). Wave w:
    // t = t0 + 4w + (lane>>4); h-sets 0..3 = B's Bc..Bc+3 share each x load.
    // x read with NORMAL loads — L1/L2 still warm from Phase A (no inv).
    {
        int t0 = (bx >> 4) * 16;
        int Bc = (bx & 15) * 4;
        int w = __builtin_amdgcn_readfirstlane(tid >> 6);
        int tq = lane >> 4, eq = lane & 15;
        int t = t0 + (w << 2) + tq;
        float4 w0r0 = *(const float4*)(W0 + (eq * 4 + 0) * 4);
        float4 w0r1 = *(const float4*)(W0 + (eq * 4 + 1) * 4);
        float4 w0r2 = *(const float4*)(W0 + (eq * 4 + 2) * 4);
        float4 w0r3 = *(const float4*)(W0 + (eq * 4 + 3) * 4);
        // xg[b * 4096]: x[(b*256 + t)*64 + eq*4], b-stride 4096 float4s
        const float4* xg = (const float4*)(x + ((size_t)t * 64) + eq * 4);
        float4 qm1[4], qb[4], vt[4], acc[4];
        float4 xA = xg[0];
        float4 xB = xg[4096];
#pragma unroll
        for (int h = 0; h < 4; ++h) {
            float4 v = f4scale(psm_s[h][0], xA);
            vt[h] = f4scale(psm_s[h][1], xB);
            qm1[h] = v;
            qb[h] = f4max(v, vt[h]);
            acc[h] = make_float4(0, 0, 0, 0);
        }
#pragma unroll 4
        for (int bl = 0; bl < 62; ++bl) {
            float4 xn = xg[(size_t)(bl + 2) * 4096];
#pragma unroll
            for (int h = 0; h < 4; ++h) {
                float4 vn = f4scale(psm_s[h][bl + 2], xn);
                float4 q1 = f4max(vt[h], vn);
                acc[h] = f4add(acc[h], f4max(qm1[h], q1));
                qm1[h] = qb[h]; qb[h] = q1; vt[h] = vn;
            }
        }
#pragma unroll
        for (int h = 0; h < 4; ++h) {
            acc[h] = f4add(acc[h], f4max(qm1[h], vt[h]));   // win[62] = max(q61, q63)
            acc[h] = f4add(acc[h], qb[h]);                  // win[63] = q62
            float4 a = acc[h];
            float4 hh = f4fma(a.x, w0r0, f4fma(a.y, w0r1,
                       f4fma(a.z, w0r2, f4scale(a.w, w0r3))));
            for (int m = 1; m <= 8; m <<= 1) {
                hh.x += __shfl_xor(hh.x, m, 64);
                hh.y += __shfl_xor(hh.y, m, 64);
                hh.z += __shfl_xor(hh.z, m, 64);
                hh.w += __shfl_xor(hh.w, m, 64);
            }
            if (eq == 0) {
                int B = Bc + h;
                float4 r = make_float4(fmaxf(hh.x, 0.f), fmaxf(hh.y, 0.f),
                                       fmaxf(hh.z, 0.f), fmaxf(hh.w, 0.f));
                store_f4_llc(h0 + (size_t)(B * 256 + t) * 4, r);
            }
        }
    }
    sync_point(bx, snap2, &g_gen2, bx < 64);   // producers bx>=64 arrive & exit

    // ---------------- Phase D: tail (bid = bx); h0 via LLC loads -----------
    if (bx < 64) {
        int bid = bx;
        {
            int q = tid >> 6, s2 = (tid & 63) * 4;
            *(float4*)(row + q * 260 + s2) = load_f4_llc(h0 + (size_t)bid * 1024 + tid * 4);
        }
        __syncthreads();
        {
            int j = tid >> 2, q = tid & 3;
            const float* hj = h0 + (size_t)j * 1024 + q * 256;
            const float4* ri = (const float4*)(row + q * 260);
            float4 s4 = make_float4(0, 0, 0, 0);
#pragma unroll 8
            for (int kk = 0; kk < 64; ++kk)
                s4 = f4fma4(ri[kk], load_f4_llc(hj + kk * 4), s4);
            part[tid] = s4.x + s4.y + s4.z + s4.w;
        }
        __syncthreads();
        if (tid < 64) {
            float z = (part[lane * 4] + part[lane * 4 + 1] + part[lane * 4 + 2]
                       + part[lane * 4 + 3]) * (1.0f / 256.0f);
            psmD[lane] = wave_sparsemax(z, lane);
        }
        __syncthreads();
        int w = __builtin_amdgcn_readfirstlane(tid >> 6);
        int rc = lane & 3;
        float psum = 0.f;
#pragma unroll
        for (int gg = 0; gg < 4; ++gg) {
            int tbase = w * 64 + gg * 16;
            const float* xb = h0 + (size_t)tbase * 4 + lane;   // h0 b-stride 1024 floats
            float v0 = psmD[0] * load_f_llc(xb);
            float v1 = psmD[1] * load_f_llc(xb + 1024);
            float qm1s = v0, qbs = fmaxf(v0, v1), vts = v1, accs = 0.f;
#pragma unroll 8
            for (int bl = 0; bl < 62; ++bl) {
                float vn = psmD[bl + 2] * load_f_llc(xb + (size_t)(bl + 2) * 1024);
                float q1 = fmaxf(vts, vn);
                accs += fmaxf(qm1s, q1);
                qm1s = qbs; qbs = q1; vts = vn;
            }
            accs += fmaxf(qm1s, vts);
            accs += qbs;
            int base = lane & ~3;
            float b0 = __shfl(accs, base + 0, 64);
            float b1 = __shfl(accs, base + 1, 64);
            float b2 = __shfl(accs, base + 2, 64);
            float b3 = __shfl(accs, base + 3, 64);
            float h = b0 * W1[rc] + b1 * W1[4 + rc] + b2 * W1[8 + rc] + b3 * W1[12 + rc];
            psum += fmaxf(h, 0.f);
        }
        for (int m = 4; m <= 32; m <<= 1) psum += __shfl_xor(psum, m, 64);
        if (lane < 4) red[w * 4 + lane] = psum;
        __syncthreads();
        if (tid < 64) {
            float pooled = 0.f;
            if (lane < 4)
                pooled = (red[lane] + red[4 + lane] + red[8 + lane] + red[12 + lane])
                         * (1.0f / 256.0f);
            float q0 = __shfl(pooled, 0, 64), q1 = __shfl(pooled, 1, 64);
            float q2 = __shfl(pooled, 2, 64), q3 = __shfl(pooled, 3, 64);
            float logit = -INFINITY;
            if (lane < 8)
                logit = q0 * Wp[lane] + q1 * Wp[8 + lane]
                      + q2 * Wp[16 + lane] + q3 * Wp[24 + lane];
            float mx = logit;
            for (int m = 4; m >= 1; m >>= 1) mx = fmaxf(mx, __shfl_xor(mx, m, 8));
            float e = (lane < 8) ? __expf(logit - mx) : 0.f;
            float s = e;
            for (int m = 4; m >= 1; m >>= 1) s += __shfl_xor(s, m, 8);
            if (lane < 8) out[bid * 8 + lane] = e / s;
        }
    }
}

extern "C" void kernel_launch(void* const* d_in, const int* in_sizes, int n_in,
                              void* d_out, int out_size, void* d_ws, size_t ws_size,
                              hipStream_t stream) {
    const float* x  = (const float*)d_in[0];   // [64,256,64]
    const float* W0 = (const float*)d_in[1];   // [64,4]
    const float* W1 = (const float*)d_in[2];   // [4,4]
    const float* Wp = (const float*)d_in[3];   // [4,8]
    float* out = (float*)d_out;                // [64,8]

    char* ws = (char*)d_ws;
    float* P  = (float*)ws;                    // 4 MB partials (LLC-resident)
    float* h0 = (float*)(ws + (4u << 20));     // 256 KB

    fused_gcn<<<256, 256, 0, stream>>>(x, W0, W1, Wp, P, h0, out);
}

// Round 10
// 115.481 us; speedup vs baseline: 1.2969x; 1.2969x over previous
//
#include <hip/hip_runtime.h>
#include <math.h>

__device__ __forceinline__ float4 f4max(float4 a, float4 b) {
    return make_float4(fmaxf(a.x, b.x), fmaxf(a.y, b.y), fmaxf(a.z, b.z), fmaxf(a.w, b.w));
}
__device__ __forceinline__ float4 f4scale(float s, float4 v) {
    return make_float4(s * v.x, s * v.y, s * v.z, s * v.w);
}
__device__ __forceinline__ float4 f4add(float4 a, float4 b) {
    return make_float4(a.x + b.x, a.y + b.y, a.z + b.z, a.w + b.w);
}
__device__ __forceinline__ float4 f4fma(float a, float4 b, float4 c) {  // scalar*vec+vec
    return make_float4(fmaf(a, b.x, c.x), fmaf(a, b.y, c.y), fmaf(a, b.z, c.z), fmaf(a, b.w, c.w));
}
__device__ __forceinline__ float4 f4fma4(float4 a, float4 b, float4 c) { // elementwise
    return make_float4(fmaf(a.x, b.x, c.x), fmaf(a.y, b.y, c.y),
                       fmaf(a.z, b.z, c.z), fmaf(a.w, b.w, c.w));
}

// agent-scope (sc1) relaxed stores: data goes to LLC, visible cross-XCD after
// vmcnt(0) drain — no wbl2 flush needed (R4/R5-verified, absmax 0.0).
// NOTE (R6/R9 falsifications): keep this exact 4x4B form and keep consumers
// on the NORMAL cached load path — 8B variants / LLC-direct loads both
// regressed when bundled with other changes.
__device__ __forceinline__ void store_f4_llc(float* p, float4 v) {
    __hip_atomic_store(p + 0, v.x, __ATOMIC_RELAXED, __HIP_MEMORY_SCOPE_AGENT);
    __hip_atomic_store(p + 1, v.y, __ATOMIC_RELAXED, __HIP_MEMORY_SCOPE_AGENT);
    __hip_atomic_store(p + 2, v.z, __ATOMIC_RELAXED, __HIP_MEMORY_SCOPE_AGENT);
    __hip_atomic_store(p + 3, v.w, __ATOMIC_RELAXED, __HIP_MEMORY_SCOPE_AGENT);
}

// Wave-level sparsemax (verified R2-R9): lane holds element `lane` of a 64-vector.
__device__ __forceinline__ float wave_sparsemax(float z, int lane) {
    float v = z;
    for (int k = 2; k <= 64; k <<= 1) {
        bool desc = (lane & k) == 0;
        for (int j = k >> 1; j > 0; j >>= 1) {
            float other = __shfl_xor(v, j, 64);
            bool lower = (lane & j) == 0;
            float mn = fminf(v, other), mx = fmaxf(v, other);
            v = (desc ^ lower) ? mn : mx;
        }
    }
    float c = v;
    for (int d = 1; d < 64; d <<= 1) {
        float n = __shfl_up(c, d, 64);
        if (lane >= d) c += n;
    }
    bool sup = (1.0f + (float)(lane + 1) * v) > c;
    int ksel = __popcll(__ballot(sup));
    float zk = __shfl(c, ksel - 1, 64);
    float tau = (zk - 1.0f) / (float)ksel;
    return fmaxf(z - tau, 0.f);
}

// ---------------------------------------------------------------------------
// Relaxed-only sync point (R4/R5-verified; 2 syncs — R7 proved each extra
// sync costs more than it saves). Zero release ops (no buffer_wbl2). Data
// visibility via sc1 stores drained by __syncthreads()'s vmcnt(0). Arrival:
// relaxed tree fetch_adds (16 lines of 16, then 16 leaders on one line;
// monotonic counters, a%16==15 elects — no resets, graph-replay-safe). Last
// leader bumps generation (relaxed). Waiters spin relaxed, then ONE acquire
// fence (buffer_inv) — KEEP IT: R9 proved removing it (LLC-direct reads)
// costs +33us; the cached read path it enables is worth far more.
// ---------------------------------------------------------------------------
__device__ unsigned g_grp[16 * 64];   // one counter per 256B line
__device__ unsigned g_glb;
__device__ unsigned g_gen1;
__device__ unsigned g_gen2;

__device__ __forceinline__ void sync_point(int bx, unsigned snap, unsigned* genp,
                                           bool wait) {
    __syncthreads();   // vmcnt(0): this block's sc1 stores are acked at LLC
    if (threadIdx.x == 0) {
        unsigned a = __hip_atomic_fetch_add(&g_grp[(bx & 15) << 6], 1u,
                                            __ATOMIC_RELAXED, __HIP_MEMORY_SCOPE_AGENT);
        if ((a & 15u) == 15u) {
            unsigned ga = __hip_atomic_fetch_add(&g_glb, 1u, __ATOMIC_RELAXED,
                                                 __HIP_MEMORY_SCOPE_AGENT);
            if ((ga & 15u) == 15u)
                __hip_atomic_fetch_add(genp, 1u, __ATOMIC_RELAXED,
                                       __HIP_MEMORY_SCOPE_AGENT);
        }
        if (wait) {
            while (__hip_atomic_load(genp, __ATOMIC_RELAXED,
                                     __HIP_MEMORY_SCOPE_AGENT) == snap)
                __builtin_amdgcn_s_sleep(1);
            __builtin_amdgcn_fence(__ATOMIC_ACQUIRE, "agent");   // buffer_inv
        }
    }
    if (wait) __syncthreads();
}

// ---------------------------------------------------------------------------
// Fused pipeline, ONE plain kernel, 256 blocks x 256 threads.
// Mapping (R5-verified optimum): 256 blocks = 16 t-chunks(16 t) x 16
// B-chunks(4 B) — balances P-read redundancy (16x) vs x re-reads (16x),
// 128 MB total LLC traffic (minimum over the decomposition family).
// Phase A : gram partials -> P via sc1 stores.          [sync1]
// Phase B'': wave w reduces gram row Bc+w (bitwise-identical summation order
//            to the verified reduce_sm) + sparsemax -> LDS psm_s[4][64].
// Phase C : agg0+W0+relu -> h0 via sc1 stores; wave w covers t-slice
//          t0+4w+(lane>>4), all 4 B's (h-sets) share each x load.  [sync2]
// Phase D : tail (blocks 0..63; others arrive & exit).
// ---------------------------------------------------------------------------
__global__ __launch_bounds__(256)
void fused_gcn(const float* __restrict__ x, const float* __restrict__ W0,
               const float* __restrict__ W1, const float* __restrict__ Wp,
               float* __restrict__ P, float* __restrict__ h0,
               float* __restrict__ out) {
    __shared__ float xsT[64][68];                 // Phase A
    __shared__ float pstg[4][4][64];              // Phase B'' quarter sums
    __shared__ float psm_s[4][64];                // Phase B'' sparsemax out
    __shared__ __align__(16) float row[4 * 260];  // Phase D
    __shared__ float part[256];                   // Phase D
    __shared__ float psmD[64];                    // Phase D
    __shared__ float red[16];                     // Phase D

    int tid = threadIdx.x;
    int bx = blockIdx.x;
    int lane = tid & 63;

    unsigned snap1 = 0, snap2 = 0;
    if (tid == 0) {
        snap1 = __hip_atomic_load(&g_gen1, __ATOMIC_RELAXED, __HIP_MEMORY_SCOPE_AGENT);
        snap2 = __hip_atomic_load(&g_gen2, __ATOMIC_RELAXED, __HIP_MEMORY_SCOPE_AGENT);
    }

    // ---------------- Phase A: gram partials (R3-verified structure) -------
    {
        int k0 = bx * 64;
#pragma unroll
        for (int it = 0; it < 4; ++it) {
            int f = it * 256 + tid;
            int i = f >> 4, k4 = (f & 15) * 4;
            float4 v = *(const float4*)(x + (size_t)i * 16384 + k0 + k4);
            xsT[k4 + 0][i] = v.x; xsT[k4 + 1][i] = v.y;
            xsT[k4 + 2][i] = v.z; xsT[k4 + 3][i] = v.w;
        }
        __syncthreads();
        int ti = (tid >> 4) * 4, tj = (tid & 15) * 4;
        float4 a0 = make_float4(0, 0, 0, 0), a1 = a0, a2 = a0, a3 = a0;
#pragma unroll 8
        for (int k = 0; k < 64; ++k) {
            float4 a = *(const float4*)&xsT[k][ti];
            float4 b = *(const float4*)&xsT[k][tj];
            a0 = f4fma(a.x, b, a0); a1 = f4fma(a.y, b, a1);
            a2 = f4fma(a.z, b, a2); a3 = f4fma(a.w, b, a3);
        }
        float* basep = P + ((size_t)bx << 12);
        store_f4_llc(basep + (ti + 0) * 64 + tj, a0);
        store_f4_llc(basep + (ti + 1) * 64 + tj, a1);
        store_f4_llc(basep + (ti + 2) * 64 + tj, a2);
        store_f4_llc(basep + (ti + 3) * 64 + tj, a3);
    }
    sync_point(bx, snap1, &g_gen1, true);

    // ---------------- Phase B'': per-wave 1-row reduce + sparsemax ---------
    // Wave w reduces gram row Bc+w. Lane (sub=lane>>4, c16=lane&15) sums
    // quarter sub (64 sequential chunks, LEFT-ASSOC — bitwise identical to
    // the verified reduce_sm). Cross-quarter combine scalar left-assoc via
    // LDS. Normal cached loads (R9: LLC-direct here costs +33us).
    {
        int w4 = tid >> 6;
        int Bc = (bx & 15) * 4;
        int rowi = Bc + w4;
        int sub = (tid & 63) >> 4;
        int c16 = tid & 15;
        const float* pb = P + (size_t)rowi * 64 + c16 * 4;
        int cbase = sub * 64;
        float4 g = make_float4(0, 0, 0, 0);
#pragma unroll 8
        for (int c = 0; c < 64; ++c)
            g = f4add(g, *(const float4*)(pb + ((size_t)(cbase + c) << 12)));
        *(float4*)&pstg[w4][sub][c16 * 4] = g;
        __syncthreads();
        {
            float z = (((pstg[w4][0][lane] + pstg[w4][1][lane])
                        + pstg[w4][2][lane]) + pstg[w4][3][lane]) * (1.0f / 256.0f);
            psm_s[w4][lane] = wave_sparsemax(z, lane);
        }
        __syncthreads();
    }

    // ---------------- Phase C: agg0 + W0 + relu -> h0 ----------------------
    // Block: t0 = (bx>>4)*16 (16 t's), Bc = (bx&15)*4 (4 B's). Wave w:
    // t = t0 + 4w + (lane>>4); h-sets 0..3 = B's Bc..Bc+3 share each x load.
    {
        int t0 = (bx >> 4) * 16;
        int Bc = (bx & 15) * 4;
        int w = __builtin_amdgcn_readfirstlane(tid >> 6);
        int tq = lane >> 4, eq = lane & 15;
        int t = t0 + (w << 2) + tq;
        float4 w0r0 = *(const float4*)(W0 + (eq * 4 + 0) * 4);
        float4 w0r1 = *(const float4*)(W0 + (eq * 4 + 1) * 4);
        float4 w0r2 = *(const float4*)(W0 + (eq * 4 + 2) * 4);
        float4 w0r3 = *(const float4*)(W0 + (eq * 4 + 3) * 4);
        // xg[b * 4096]: x[(b*256 + t)*64 + eq*4], b-stride 4096 float4s
        const float4* xg = (const float4*)(x + ((size_t)t * 64) + eq * 4);
        float4 qm1[4], qb[4], vt[4], acc[4];
        float4 xA = xg[0];
        float4 xB = xg[4096];
#pragma unroll
        for (int h = 0; h < 4; ++h) {
            float4 v = f4scale(psm_s[h][0], xA);
            vt[h] = f4scale(psm_s[h][1], xB);
            qm1[h] = v;
            qb[h] = f4max(v, vt[h]);
            acc[h] = make_float4(0, 0, 0, 0);
        }
#pragma unroll 4
        for (int bl = 0; bl < 62; ++bl) {
            float4 xn = xg[(size_t)(bl + 2) * 4096];
#pragma unroll
            for (int h = 0; h < 4; ++h) {
                float4 vn = f4scale(psm_s[h][bl + 2], xn);
                float4 q1 = f4max(vt[h], vn);
                acc[h] = f4add(acc[h], f4max(qm1[h], q1));
                qm1[h] = qb[h]; qb[h] = q1; vt[h] = vn;
            }
        }
#pragma unroll
        for (int h = 0; h < 4; ++h) {
            acc[h] = f4add(acc[h], f4max(qm1[h], vt[h]));   // win[62] = max(q61, q63)
            acc[h] = f4add(acc[h], qb[h]);                  // win[63] = q62
            float4 a = acc[h];
            float4 hh = f4fma(a.x, w0r0, f4fma(a.y, w0r1,
                       f4fma(a.z, w0r2, f4scale(a.w, w0r3))));
            for (int m = 1; m <= 8; m <<= 1) {
                hh.x += __shfl_xor(hh.x, m, 64);
                hh.y += __shfl_xor(hh.y, m, 64);
                hh.z += __shfl_xor(hh.z, m, 64);
                hh.w += __shfl_xor(hh.w, m, 64);
            }
            if (eq == 0) {
                int B = Bc + h;
                float4 r = make_float4(fmaxf(hh.x, 0.f), fmaxf(hh.y, 0.f),
                                       fmaxf(hh.z, 0.f), fmaxf(hh.w, 0.f));
                store_f4_llc(h0 + (size_t)(B * 256 + t) * 4, r);
            }
        }
    }
    sync_point(bx, snap2, &g_gen2, bx < 64);   // producers bx>=64 arrive & exit

    // ---------------- Phase D: tail (bid = bx; R5 verbatim) ----------------
    if (bx < 64) {
        int bid = bx;
        {
            int q = tid >> 6, s2 = (tid & 63) * 4;
            *(float4*)(row + q * 260 + s2) = *(const float4*)(h0 + (size_t)bid * 1024 + tid * 4);
        }
        __syncthreads();
        {
            int j = tid >> 2, q = tid & 3;
            const float4* hj = (const float4*)(h0 + (size_t)j * 1024 + q * 256);
            const float4* ri = (const float4*)(row + q * 260);
            float4 s4 = make_float4(0, 0, 0, 0);
#pragma unroll 8
            for (int kk = 0; kk < 64; ++kk) s4 = f4fma4(ri[kk], hj[kk], s4);
            part[tid] = s4.x + s4.y + s4.z + s4.w;
        }
        __syncthreads();
        if (tid < 64) {
            float z = (part[lane * 4] + part[lane * 4 + 1] + part[lane * 4 + 2]
                       + part[lane * 4 + 3]) * (1.0f / 256.0f);
            psmD[lane] = wave_sparsemax(z, lane);
        }
        __syncthreads();
        int w = __builtin_amdgcn_readfirstlane(tid >> 6);
        int rc = lane & 3;
        float psum = 0.f;
#pragma unroll
        for (int gg = 0; gg < 4; ++gg) {
            int tbase = w * 64 + gg * 16;
            const float* xb = h0 + (size_t)tbase * 4 + lane;   // h0 b-stride 1024 floats
            float v0 = psmD[0] * xb[0];
            float v1 = psmD[1] * xb[1024];
            float qm1s = v0, qbs = fmaxf(v0, v1), vts = v1, accs = 0.f;
#pragma unroll 8
            for (int bl = 0; bl < 62; ++bl) {
                float vn = psmD[bl + 2] * xb[(size_t)(bl + 2) * 1024];
                float q1 = fmaxf(vts, vn);
                accs += fmaxf(qm1s, q1);
                qm1s = qbs; qbs = q1; vts = vn;
            }
            accs += fmaxf(qm1s, vts);
            accs += qbs;
            int base = lane & ~3;
            float b0 = __shfl(accs, base + 0, 64);
            float b1 = __shfl(accs, base + 1, 64);
            float b2 = __shfl(accs, base + 2, 64);
            float b3 = __shfl(accs, base + 3, 64);
            float h = b0 * W1[rc] + b1 * W1[4 + rc] + b2 * W1[8 + rc] + b3 * W1[12 + rc];
            psum += fmaxf(h, 0.f);
        }
        for (int m = 4; m <= 32; m <<= 1) psum += __shfl_xor(psum, m, 64);
        if (lane < 4) red[w * 4 + lane] = psum;
        __syncthreads();
        if (tid < 64) {
            float pooled = 0.f;
            if (lane < 4)
                pooled = (red[lane] + red[4 + lane] + red[8 + lane] + red[12 + lane])
                         * (1.0f / 256.0f);
            float q0 = __shfl(pooled, 0, 64), q1 = __shfl(pooled, 1, 64);
            float q2 = __shfl(pooled, 2, 64), q3 = __shfl(pooled, 3, 64);
            float logit = -INFINITY;
            if (lane < 8)
                logit = q0 * Wp[lane] + q1 * Wp[8 + lane]
                      + q2 * Wp[16 + lane] + q3 * Wp[24 + lane];
            float mx = logit;
            for (int m = 4; m >= 1; m >>= 1) mx = fmaxf(mx, __shfl_xor(mx, m, 8));
            float e = (lane < 8) ? __expf(logit - mx) : 0.f;
            float s = e;
            for (int m = 4; m >= 1; m >>= 1) s += __shfl_xor(s, m, 8);
            if (lane < 8) out[bid * 8 + lane] = e / s;
        }
    }
}

extern "C" void kernel_launch(void* const* d_in, const int* in_sizes, int n_in,
                              void* d_out, int out_size, void* d_ws, size_t ws_size,
                              hipStream_t stream) {
    const float* x  = (const float*)d_in[0];   // [64,256,64]
    const float* W0 = (const float*)d_in[1];   // [64,4]
    const float* W1 = (const float*)d_in[2];   // [4,4]
    const float* Wp = (const float*)d_in[3];   // [4,8]
    float* out = (float*)d_out;                // [64,8]

    char* ws = (char*)d_ws;
    float* P  = (float*)ws;                    // 4 MB partials (LLC-resident)
    float* h0 = (float*)(ws + (4u << 20));     // 256 KB

    fused_gcn<<<256, 256, 0, stream>>>(x, W0, W1, Wp, P, h0, out);
}